// Round 1
// baseline (64762.616 us; speedup 1.0000x reference)
//
#include <hip/hip_runtime.h>
#include <cstdint>
#include <cstddef>

// ---------------------------------------------------------------------------
// AttentionalSeq2seq on MI355X — round 0: correctness-first multi-launch design.
// Encoder GRU (1024 serial steps) with fused online-softmax Luong attention,
// decoder GRU+Linear (256 serial steps), final output GEMM. All fp32.
// One kernel launch per serial phase; stream order provides the global barrier
// (and cross-XCD visibility). Persistent/cooperative + bf16 MFMA are later rounds.
// ---------------------------------------------------------------------------

namespace {
constexpr int H_    = 1024;
constexpr int B_    = 64;
constexpr int SIN_  = 1024;
constexpr int SOUT_ = 256;
constexpr int OUT_  = 512;
constexpr int JW    = 4;          // hidden columns per workgroup
constexpr int NWG   = H_ / JW;    // 256 workgroups
constexpr int KC    = 128;        // K-chunk staged in LDS
constexpr int LS    = KC + 1;     // pad -> stride 129: 2-way aliasing max (free)

// workspace layout (floats)
constexpr size_t OFF_H0    = 0;                                  // h ping  [B][H]
constexpr size_t OFF_H1    = OFF_H0 + (size_t)B_ * H_;           // h pong  [B][H]
constexpr size_t OFF_E     = OFF_H1 + (size_t)B_ * H_;           // energies [SIN+1][B]
constexpr size_t OFF_ML    = OFF_E + (size_t)(SIN_ + 1) * B_;    // running (m,l) [2 slots][2][B]
constexpr size_t OFF_CTX   = OFF_ML + 4 * B_;                    // ctx accumulator [B][H]
constexpr size_t OFF_CTERM = OFF_CTX + (size_t)B_ * H_;          // Wc2*ctx + cb    [B][H]
constexpr size_t OFF_HGRU  = OFF_CTERM + (size_t)B_ * H_;        // decoder GRU out [B][H]
constexpr size_t WS_FLOATS = OFF_HGRU + (size_t)B_ * H_;         // ~394K floats ~1.6 MB
}  // namespace

// Online-softmax context update for encoder hidden h_u with finalized energy E[u].
// Every WG updates its own 4-column slice of ctx_acc; (m,l) are recomputed
// redundantly (identical values) and written to the u%2 slot (read slot (u-1)%2).
__device__ __forceinline__ void ctx_update_body(int u, const float* __restrict__ h_u,
                                                const float* __restrict__ E,
                                                float* __restrict__ ml,
                                                float* __restrict__ ctx_acc,
                                                int t, int j0) {
  int b = t >> 2, jj = t & 3;
  int rsl = ((u - 1) & 1) * 2 * B_;
  int wsl = (u & 1) * 2 * B_;
  float m_old = ml[rsl + b];
  float l_old = ml[rsl + B_ + b];
  float e = E[(size_t)u * B_ + b];
  float m_new, scale, w, l_new;
  if (l_old == 0.f) {  // first update (workspace memset to 0)
    m_new = e; scale = 0.f; w = 1.f; l_new = 1.f;
  } else {
    m_new = fmaxf(m_old, e);
    scale = expf(m_old - m_new);
    w = expf(e - m_new);
    l_new = l_old * scale + w;
  }
  int idx = b * H_ + j0 + jj;
  ctx_acc[idx] = ctx_acc[idx] * scale + w * h_u[idx];
  if (jj == 0) { ml[wsl + b] = m_new; ml[wsl + B_ + b] = l_new; }
}

// One GRU step. NROWS=16 (encoder: 12 gate rows + 4 attention rows, online
// attention fused, lagged one phase) or NROWS=12 (decoder GRU only).
// Each WG owns columns [j0, j0+4). Phase p: reads h_in=h_p (full), writes
// h_out[own slice]=h_{p+1}; for encoder also accumulates E[p] for h_p and
// applies the ctx update for h_{p-1} (stored in the h_out buffer, own slice,
// read before overwrite by the same thread).
template <int NROWS, bool IS_ENC>
__global__ __launch_bounds__(256) void step_kernel(
    const float* __restrict__ xseq, int xstride, int p,
    const float* __restrict__ Wih, const float* __restrict__ Whh,
    const float* __restrict__ bih, const float* __restrict__ bhh,
    const float* __restrict__ attnW, const float* __restrict__ attnb,
    const float* __restrict__ h_in, float* __restrict__ h_out,
    float* __restrict__ E, float* __restrict__ ml, float* __restrict__ ctx_acc) {
  __shared__ float hs[64 * LS];    // h chunk   [64][KC]
  __shared__ float wsm[16 * LS];   // weight rows [NROWS][KC]
  __shared__ float ghs[64 * 17];   // gemm results [64 b][16 rows]

  const int t = threadIdx.x;
  const int j0 = blockIdx.x * JW;

  if (IS_ENC && p >= 2) {
    // ctx update for h_{p-1}: lives in the h_out buffer (ping-pong depth 2);
    // each element read only by the thread that later overwrites it.
    ctx_update_body(p - 1, h_out, E, ml, ctx_acc, t, j0);
  }

  const int b2 = t & 31;   // batch pair
  const int rp = t >> 5;   // row pair
  float a00 = 0.f, a01 = 0.f, a10 = 0.f, a11 = 0.f;

  for (int k0 = 0; k0 < H_; k0 += KC) {
    for (int q = t; q < 64 * (KC / 4); q += 256) {  // stage h chunk (float4, coalesced)
      int row = q >> 5, c4 = q & 31;
      float4 v = *reinterpret_cast<const float4*>(h_in + (size_t)row * H_ + k0 + c4 * 4);
      float* d = hs + row * LS + c4 * 4;
      d[0] = v.x; d[1] = v.y; d[2] = v.z; d[3] = v.w;
    }
    for (int q = t; q < NROWS * (KC / 4); q += 256) {  // stage weight rows
      int r = q >> 5, c4 = q & 31;
      const float* src;
      if (r < 12) src = Whh + (size_t)((r >> 2) * H_ + j0 + (r & 3)) * H_;  // gate g=r>>2, col j0+(r&3)
      else        src = attnW + (size_t)(j0 + (r - 12)) * H_;
      float4 v = *reinterpret_cast<const float4*>(src + k0 + c4 * 4);
      float* d = wsm + r * LS + c4 * 4;
      d[0] = v.x; d[1] = v.y; d[2] = v.z; d[3] = v.w;
    }
    __syncthreads();
    if (2 * rp < NROWS) {
      const float* hp0 = hs + (2 * b2) * LS;
      const float* hp1 = hs + (2 * b2 + 1) * LS;
      const float* wp0 = wsm + (2 * rp) * LS;
      const float* wp1 = wsm + (2 * rp + 1) * LS;
#pragma unroll 8
      for (int kk = 0; kk < KC; ++kk) {
        float h0 = hp0[kk], h1 = hp1[kk];
        float w0 = wp0[kk], w1 = wp1[kk];
        a00 = fmaf(h0, w0, a00); a01 = fmaf(h0, w1, a01);
        a10 = fmaf(h1, w0, a10); a11 = fmaf(h1, w1, a11);
      }
    }
    __syncthreads();
  }

  if (2 * rp < NROWS) {
    ghs[(2 * b2) * 17 + 2 * rp] = a00;
    ghs[(2 * b2) * 17 + 2 * rp + 1] = a01;
    ghs[(2 * b2 + 1) * 17 + 2 * rp] = a10;
    ghs[(2 * b2 + 1) * 17 + 2 * rp + 1] = a11;
  }
  __syncthreads();

  {  // gate math: thread (b = t>>2, jj = t&3) owns output column j0+jj
    int b = t >> 2, jj = t & 3;
    int j = j0 + jj;
    float ghr = ghs[b * 17 + jj];
    float ghz = ghs[b * 17 + 4 + jj];
    float ghn = ghs[b * 17 + 8 + jj];
    float xv = xseq[(size_t)b * xstride + p];  // input feature dim is 1
    float ir = fmaf(xv, Wih[j],          bih[j]);
    float iz = fmaf(xv, Wih[H_ + j],     bih[H_ + j]);
    float inn= fmaf(xv, Wih[2 * H_ + j], bih[2 * H_ + j]);
    float hr = ghr + bhh[j];
    float hz = ghz + bhh[H_ + j];
    float hn = ghn + bhh[2 * H_ + j];
    float r = 1.f / (1.f + expf(-(ir + hr)));
    float z = 1.f / (1.f + expf(-(iz + hz)));
    float n = tanhf(fmaf(r, hn, inn));
    float hcur = h_in[(size_t)b * H_ + j];
    h_out[(size_t)b * H_ + j] = (1.f - z) * n + z * hcur;

    if (IS_ENC) {  // energy contribution of h_p: h_p[j] * ((A h_p)[j] + attn_b[j])
      float att = ghs[b * 17 + 12 + jj];
      float ec = hcur * (att + attnb[j]);
      ec += __shfl_xor(ec, 1);
      ec += __shfl_xor(ec, 2);
      if (jj == 0) atomicAdd(&E[(size_t)p * B_ + b], ec);
    }
  }
}

// Standalone ctx update (encoder tail: u = 1023, 1024).
__global__ __launch_bounds__(256) void ctx_update_kernel(
    int u, const float* __restrict__ h_u, const float* __restrict__ E,
    float* __restrict__ ml, float* __restrict__ ctx_acc) {
  ctx_update_body(u, h_u, E, ml, ctx_acc, threadIdx.x, blockIdx.x * JW);
}

// Energy of the final encoder hidden h_1024 (no GRU step attached to it).
__global__ __launch_bounds__(256) void energy_kernel(
    const float* __restrict__ h, const float* __restrict__ attnW,
    const float* __restrict__ attnb, float* __restrict__ Edst) {
  __shared__ float hs[64 * LS];
  __shared__ float wsm[4 * LS];
  const int t = threadIdx.x;
  const int j0 = blockIdx.x * JW;
  const int b = t >> 2, jj = t & 3;
  float acc = 0.f;
  for (int k0 = 0; k0 < H_; k0 += KC) {
    for (int q = t; q < 64 * (KC / 4); q += 256) {
      int row = q >> 5, c4 = q & 31;
      float4 v = *reinterpret_cast<const float4*>(h + (size_t)row * H_ + k0 + c4 * 4);
      float* d = hs + row * LS + c4 * 4;
      d[0] = v.x; d[1] = v.y; d[2] = v.z; d[3] = v.w;
    }
    for (int q = t; q < 4 * (KC / 4); q += 256) {
      int r = q >> 5, c4 = q & 31;
      float4 v = *reinterpret_cast<const float4*>(attnW + (size_t)(j0 + r) * H_ + k0 + c4 * 4);
      float* d = wsm + r * LS + c4 * 4;
      d[0] = v.x; d[1] = v.y; d[2] = v.z; d[3] = v.w;
    }
    __syncthreads();
    const float* hp = hs + b * LS;
    const float* wp = wsm + jj * LS;
#pragma unroll 8
    for (int kk = 0; kk < KC; ++kk) acc = fmaf(hp[kk], wp[kk], acc);
    __syncthreads();
  }
  float ec = h[(size_t)b * H_ + j0 + jj] * (acc + attnb[j0 + jj]);
  ec += __shfl_xor(ec, 1);
  ec += __shfl_xor(ec, 2);
  if (jj == 0) atomicAdd(&Edst[b], ec);
}

// dst[b][j] = (1/linv[b] if linv) * sum_k W[j*wstride+woff+k]*src[b][k]
//           + bias[j] (if bias) + add[b][j] (if add)
// Used for: ctx_term = Wc2*(ctx_acc/l) + cb ; decoder h_next = Wc1*hgru + ctx_term ;
// final out = out_W*hgru + out_b.
__global__ __launch_bounds__(256) void lin_kernel(
    const float* __restrict__ src, const float* __restrict__ W, int wstride, int woff,
    const float* __restrict__ add, const float* __restrict__ bias,
    const float* __restrict__ linv, float* __restrict__ dst, int NJ) {
  __shared__ float hs[64 * LS];
  __shared__ float wsm[4 * LS];
  const int t = threadIdx.x;
  const int jw = NJ >> 8;  // NJ / 256 workgroups
  const int j0 = blockIdx.x * jw;
  const int b = t / jw;
  const int jj = t % jw;
  float acc = 0.f;
  for (int k0 = 0; k0 < H_; k0 += KC) {
    for (int q = t; q < 64 * (KC / 4); q += 256) {
      int row = q >> 5, c4 = q & 31;
      float4 v = *reinterpret_cast<const float4*>(src + (size_t)row * H_ + k0 + c4 * 4);
      float* d = hs + row * LS + c4 * 4;
      d[0] = v.x; d[1] = v.y; d[2] = v.z; d[3] = v.w;
    }
    for (int q = t; q < jw * (KC / 4); q += 256) {
      int r = q >> 5, c4 = q & 31;
      float4 v = *reinterpret_cast<const float4*>(W + (size_t)(j0 + r) * wstride + woff + k0 + c4 * 4);
      float* d = wsm + r * LS + c4 * 4;
      d[0] = v.x; d[1] = v.y; d[2] = v.z; d[3] = v.w;
    }
    __syncthreads();
    if (b < B_) {
      const float* hp = hs + b * LS;
      const float* wp = wsm + jj * LS;
#pragma unroll 8
      for (int kk = 0; kk < KC; ++kk) acc = fmaf(hp[kk], wp[kk], acc);
    }
    __syncthreads();
  }
  if (b < B_) {
    float val = acc;
    if (linv) val *= (1.f / linv[b]);
    if (bias) val += bias[j0 + jj];
    if (add)  val += add[(size_t)b * NJ + j0 + jj];
    dst[(size_t)b * NJ + j0 + jj] = val;
  }
}

extern "C" void kernel_launch(void* const* d_in, const int* in_sizes, int n_in,
                              void* d_out, int out_size, void* d_ws, size_t ws_size,
                              hipStream_t stream) {
  const float* in_ftrs  = (const float*)d_in[0];
  const float* out_ftrs = (const float*)d_in[1];
  const float* eWih  = (const float*)d_in[2];
  const float* eWhh  = (const float*)d_in[3];
  const float* ebih  = (const float*)d_in[4];
  const float* ebhh  = (const float*)d_in[5];
  const float* dWih  = (const float*)d_in[6];
  const float* dWhh  = (const float*)d_in[7];
  const float* dbih  = (const float*)d_in[8];
  const float* dbhh  = (const float*)d_in[9];
  const float* attnW = (const float*)d_in[10];
  const float* attnb = (const float*)d_in[11];
  const float* cW    = (const float*)d_in[12];
  const float* cb    = (const float*)d_in[13];
  const float* oW    = (const float*)d_in[14];
  const float* ob    = (const float*)d_in[15];

  float* ws    = (float*)d_ws;
  float* h0    = ws + OFF_H0;
  float* h1    = ws + OFF_H1;
  float* E     = ws + OFF_E;
  float* ml    = ws + OFF_ML;
  float* ctx   = ws + OFF_CTX;
  float* cterm = ws + OFF_CTERM;
  float* hgru  = ws + OFF_HGRU;

  // zero all recurrent state (h0, energies, (m,l), ctx accumulator)
  hipMemsetAsync(d_ws, 0, WS_FLOATS * sizeof(float), stream);

  // ---- encoder: phase p computes h_{p+1}; fused E[p] (for h_p) and ctx update (h_{p-1})
  for (int p = 0; p < SIN_; ++p) {
    const float* hin = (p & 1) ? h1 : h0;
    float* hout      = (p & 1) ? h0 : h1;
    step_kernel<16, true><<<NWG, 256, 0, stream>>>(
        in_ftrs, SIN_, p, eWih, eWhh, ebih, ebhh, attnW, attnb,
        hin, hout, E, ml, ctx);
  }
  // tail: h_1024 is in h0, h_1023 in h1
  ctx_update_kernel<<<NWG, 256, 0, stream>>>(1023, h1, E, ml, ctx);
  energy_kernel<<<NWG, 256, 0, stream>>>(h0, attnW, attnb, E + (size_t)SIN_ * B_);
  ctx_update_kernel<<<NWG, 256, 0, stream>>>(1024, h0, E, ml, ctx);
  // ctx_term = Wc2 * (ctx_acc / l) + concat_b   (final l lives in slot 0: ml[B..2B))
  lin_kernel<<<NWG, 256, 0, stream>>>(ctx, cW, 2 * H_, H_, nullptr, cb, ml + B_, cterm, H_);

  // ---- decoder: A) hgru = GRU(h_state, y_s)   B) h_state = Wc1*hgru + ctx_term
  for (int s = 0; s < SOUT_; ++s) {
    step_kernel<12, false><<<NWG, 256, 0, stream>>>(
        out_ftrs, SOUT_, s, dWih, dWhh, dbih, dbhh, nullptr, nullptr,
        h0, hgru, nullptr, nullptr, nullptr);
    if (s + 1 < SOUT_)
      lin_kernel<<<NWG, 256, 0, stream>>>(hgru, cW, 2 * H_, 0, cterm, nullptr, nullptr, h0, H_);
  }

  // ---- final projection of last hgru
  lin_kernel<<<NWG, 256, 0, stream>>>(hgru, oW, H_, 0, nullptr, ob, nullptr, (float*)d_out, OUT_);

  (void)in_sizes; (void)n_in; (void)out_size; (void)ws_size;
}

// Round 2
// 45704.510 us; speedup vs baseline: 1.4170x; 1.4170x over previous
//
#include <hip/hip_runtime.h>
#include <cstdint>
#include <cstddef>

// ---------------------------------------------------------------------------
// AttentionalSeq2seq on MI355X — round 1: transposed-state layout.
// All recurrent state stored as hT[H][B=64] (lane = batch). One wave per
// hidden column: weights are wave-uniform -> s_load scalar operands; h comes
// from LDS (linear layout, global_load_lds dwordx4 double-buffered staging).
// No inter-wave reduction, no big atomic contention (32-slot partial energies,
// mod-3 rotation). One launch per serial phase (stream = global barrier).
// ---------------------------------------------------------------------------

namespace {
constexpr int H_    = 1024;
constexpr int B_    = 64;
constexpr int SIN_  = 1024;
constexpr int SOUT_ = 256;
constexpr int OUT_  = 512;
constexpr int KC     = 128;        // k-rows per staged chunk (32 KB)
constexpr int NCHUNK = H_ / KC;    // 8

// workspace layout (floats)
constexpr size_t OFF_HB0   = 0;                                // hT ping [H][B]
constexpr size_t OFF_HB1   = OFF_HB0 + (size_t)H_ * B_;        // hT pong
constexpr size_t OFF_CTX   = OFF_HB1 + (size_t)H_ * B_;        // ctx accumulator (transposed)
constexpr size_t OFF_EP    = OFF_CTX + (size_t)H_ * B_;        // energy partials [3][32][64]
constexpr size_t OFF_ML    = OFF_EP + 3 * 32 * 64;             // (m,l) [2 slots][2][64]
constexpr size_t OFF_CTERM = OFF_ML + 256;                     // Wc2*context + cb (transposed)
constexpr size_t OFF_HGRU  = OFF_CTERM + (size_t)H_ * B_;      // decoder GRU out (transposed)
constexpr size_t OFF_XTE   = OFF_HGRU + (size_t)H_ * B_;       // enc inputs transposed [S_IN][B]
constexpr size_t OFF_XTD   = OFF_XTE + (size_t)SIN_ * B_;      // dec inputs transposed [S_OUT][B]
constexpr size_t WS_FLOATS = OFF_XTD + (size_t)SOUT_ * B_;     // ~416K floats ~1.7 MB
}  // namespace

// Stage k-rows [c*KC, (c+1)*KC) of srcT[1024][64] into lbuf (linear [KC][64]).
// Wave w stages rows c*KC + w*32 .. +32 via 8 global_load_lds dwordx4:
// LDS dest = uniform base + 16*lane (exactly linear), global src per-lane.
__device__ __forceinline__ void stage_chunk(const float* __restrict__ srcT,
                                            float* lbuf, int c, int w, int l) {
#pragma unroll
  for (int i = 0; i < 8; ++i) {
    const int krow = c * KC + w * 32 + i * 4 + (l >> 4);
    const float* g = srcT + (size_t)krow * 64 + (l & 15) * 4;
    float* lp = lbuf + (w * 2048 + i * 256 + l * 4);  // bytes: uniform + 16*l
    __builtin_amdgcn_global_load_lds(
        (const __attribute__((address_space(1))) void*)g,
        (__attribute__((address_space(3))) void*)lp, 16, 0, 0);
  }
}

// Online-softmax (m,l)+ctx update for step u (energy finalized in Epart[u%3]).
__device__ __forceinline__ void ctx_update_T(int u, int j, int l,
                                             const float* __restrict__ Epart,
                                             float* __restrict__ ml,
                                             float* __restrict__ ctxT,
                                             const float* __restrict__ hTu) {
  const float* Eb = Epart + (size_t)(u % 3) * 2048;
  float e = 0.f;
#pragma unroll
  for (int g = 0; g < 32; ++g) e += Eb[g * 64 + l];
  const float* mlr = ml + ((u - 1) & 1) * 128;
  float m_old = mlr[l], l_old = mlr[64 + l];
  float m_new, sc, wgt, l_new;
  if (l_old == 0.f) {  // first update
    m_new = e; sc = 0.f; wgt = 1.f; l_new = 1.f;
  } else {
    m_new = fmaxf(m_old, e);
    sc = expf(m_old - m_new);
    wgt = expf(e - m_new);
    l_new = fmaf(l_old, sc, wgt);
  }
  const size_t ci = (size_t)j * 64 + l;
  ctxT[ci] = fmaf(ctxT[ci], sc, wgt * hTu[ci]);
  if (j == 0) { float* mlw = ml + (u & 1) * 128; mlw[l] = m_new; mlw[64 + l] = l_new; }
}

// One GRU step in transposed layout. Wave = one hidden column j:
// 3 gate dots (+1 attention dot if encoder) with scalar weights, then gate
// math and the coalesced hT_out[j][*] write. Encoder also: rotate-zero of
// Epart[(p+1)%3] (WG0), ctx update for h_{p-1} (in hT_out buffer), energy
// partial atomicAdd for h_p into Epart[p%3][j&31].
template <bool IS_ENC>
__global__ __launch_bounds__(256) void stepT_kernel(
    const float* __restrict__ xT, int p,
    const float* __restrict__ Wih, const float* __restrict__ Whh,
    const float* __restrict__ bih, const float* __restrict__ bhh,
    const float* __restrict__ attnW, const float* __restrict__ attnb,
    const float* __restrict__ hT_in, float* __restrict__ hT_out,
    float* __restrict__ Epart, float* __restrict__ ml, float* __restrict__ ctxT) {
  __shared__ __attribute__((aligned(16))) float hs[2][KC * 64];
  const int t = threadIdx.x;
  const int l = t & 63;
  const int w = __builtin_amdgcn_readfirstlane(t >> 6);  // wave id (uniform)
  const int j = blockIdx.x * 4 + w;                      // hidden column (uniform)

  if (IS_ENC && blockIdx.x == 0) {  // zero the buffer written at step p+1
    float* z = Epart + (size_t)((p + 1) % 3) * 2048;
#pragma unroll
    for (int i = 0; i < 8; ++i) z[t * 8 + i] = 0.f;
  }
  if (IS_ENC && p >= 2) ctx_update_T(p - 1, j, l, Epart, ml, ctxT, hT_out);

  const float* Wr = Whh + (size_t)j * H_;
  const float* Wz = Whh + (size_t)(H_ + j) * H_;
  const float* Wn = Whh + (size_t)(2 * H_ + j) * H_;
  const float* Wa = IS_ENC ? attnW + (size_t)j * H_ : nullptr;

  float aR = 0.f, aZ = 0.f, aN = 0.f, aA = 0.f;
  stage_chunk(hT_in, &hs[0][0], 0, w, l);
  asm volatile("s_waitcnt vmcnt(0)" ::: "memory");
  __syncthreads();
  for (int c = 0; c < NCHUNK; ++c) {
    if (c + 1 < NCHUNK) stage_chunk(hT_in, &hs[(c + 1) & 1][0], c + 1, w, l);
    const float* hp = &hs[c & 1][0];
    const int kb = c * KC;
#pragma unroll 32
    for (int kk = 0; kk < KC; ++kk) {
      float h = hp[kk * 64 + l];
      aR = fmaf(h, Wr[kb + kk], aR);
      aZ = fmaf(h, Wz[kb + kk], aZ);
      aN = fmaf(h, Wn[kb + kk], aN);
      if (IS_ENC) aA = fmaf(h, Wa[kb + kk], aA);
    }
    asm volatile("s_waitcnt vmcnt(0)" ::: "memory");
    __syncthreads();
  }

  {  // gate math (scalar weights, lane = batch)
    float xv = xT[(size_t)p * 64 + l];
    float ir  = fmaf(xv, Wih[j],           bih[j]);
    float iz  = fmaf(xv, Wih[H_ + j],      bih[H_ + j]);
    float in_ = fmaf(xv, Wih[2 * H_ + j],  bih[2 * H_ + j]);
    float hr = aR + bhh[j];
    float hz = aZ + bhh[H_ + j];
    float hn = aN + bhh[2 * H_ + j];
    float r = 1.f / (1.f + expf(-(ir + hr)));
    float z = 1.f / (1.f + expf(-(iz + hz)));
    float n = tanhf(fmaf(r, hn, in_));
    float hcur = hT_in[(size_t)j * 64 + l];
    hT_out[(size_t)j * 64 + l] = fmaf(z, hcur - n, n);  // (1-z)n + z h
    if (IS_ENC) {
      float att = aA + attnb[j];
      atomicAdd(&Epart[(size_t)(p % 3) * 2048 + (size_t)(j & 31) * 64 + l], hcur * att);
    }
  }
}

// Standalone ctx update (encoder tail u = 1023, 1024).
__global__ __launch_bounds__(256) void ctx_tail_kernel(
    int u, const float* __restrict__ hTu, const float* __restrict__ Epart,
    float* __restrict__ ml, float* __restrict__ ctxT) {
  const int t = threadIdx.x, l = t & 63;
  const int w = __builtin_amdgcn_readfirstlane(t >> 6);
  ctx_update_T(u, blockIdx.x * 4 + w, l, Epart, ml, ctxT, hTu);
}

// Energy of h_1024: wave = one attention row j (1 dot), partials into Ebuf.
__global__ __launch_bounds__(256) void energy_tail_kernel(
    const float* __restrict__ hT, const float* __restrict__ attnW,
    const float* __restrict__ attnb, float* __restrict__ Ebuf) {
  __shared__ __attribute__((aligned(16))) float hs[2][KC * 64];
  const int t = threadIdx.x, l = t & 63;
  const int w = __builtin_amdgcn_readfirstlane(t >> 6);
  const int j = blockIdx.x * 4 + w;
  const float* Wa = attnW + (size_t)j * H_;
  float aA = 0.f;
  stage_chunk(hT, &hs[0][0], 0, w, l);
  asm volatile("s_waitcnt vmcnt(0)" ::: "memory");
  __syncthreads();
  for (int c = 0; c < NCHUNK; ++c) {
    if (c + 1 < NCHUNK) stage_chunk(hT, &hs[(c + 1) & 1][0], c + 1, w, l);
    const float* hp = &hs[c & 1][0];
    const int kb = c * KC;
#pragma unroll 32
    for (int kk = 0; kk < KC; ++kk) aA = fmaf(hp[kk * 64 + l], Wa[kb + kk], aA);
    asm volatile("s_waitcnt vmcnt(0)" ::: "memory");
    __syncthreads();
  }
  atomicAdd(&Ebuf[(size_t)(j & 31) * 64 + l], hT[(size_t)j * 64 + l] * (aA + attnb[j]));
}

// dstT[j][b] = sum_k W[j*wstride+woff+k]*srcT[k][b] (*1/linv[b]) (+bias[j]) (+addT[j][b])
// Wave = 2 output columns. rowmajor_out: write dst[b*NJ+j] (final output only).
__global__ __launch_bounds__(256) void linT_kernel(
    const float* __restrict__ srcT, const float* __restrict__ W, int wstride, int woff,
    const float* __restrict__ addT, const float* __restrict__ bias,
    const float* __restrict__ linv, float* __restrict__ dst, int NJ, int rowmajor_out) {
  __shared__ __attribute__((aligned(16))) float hs[2][KC * 64];
  const int t = threadIdx.x, l = t & 63;
  const int w = __builtin_amdgcn_readfirstlane(t >> 6);
  const int j0 = (blockIdx.x * 4 + w) * 2;
  const float* W0 = W + (size_t)j0 * wstride + woff;
  const float* W1 = W + (size_t)(j0 + 1) * wstride + woff;
  float a0 = 0.f, a1 = 0.f;
  stage_chunk(srcT, &hs[0][0], 0, w, l);
  asm volatile("s_waitcnt vmcnt(0)" ::: "memory");
  __syncthreads();
  for (int c = 0; c < NCHUNK; ++c) {
    if (c + 1 < NCHUNK) stage_chunk(srcT, &hs[(c + 1) & 1][0], c + 1, w, l);
    const float* hp = &hs[c & 1][0];
    const int kb = c * KC;
#pragma unroll 32
    for (int kk = 0; kk < KC; ++kk) {
      float h = hp[kk * 64 + l];
      a0 = fmaf(h, W0[kb + kk], a0);
      a1 = fmaf(h, W1[kb + kk], a1);
    }
    asm volatile("s_waitcnt vmcnt(0)" ::: "memory");
    __syncthreads();
  }
  const float inv = linv ? 1.f / linv[l] : 1.f;
#pragma unroll
  for (int ci = 0; ci < 2; ++ci) {
    const int j = j0 + ci;
    float val = (ci ? a1 : a0) * inv;
    if (bias) val += bias[j];
    if (addT) val += addT[(size_t)j * 64 + l];
    if (rowmajor_out) dst[(size_t)l * NJ + j] = val;
    else              dst[(size_t)j * 64 + l] = val;
  }
}

// x[b][s] -> xT[s][b]
__global__ __launch_bounds__(256) void transpose_kernel(
    const float* __restrict__ x, float* __restrict__ xT, int S) {
  int idx = blockIdx.x * 256 + threadIdx.x;
  int s = idx >> 6, b = idx & 63;
  xT[idx] = x[(size_t)b * S + s];
}

extern "C" void kernel_launch(void* const* d_in, const int* in_sizes, int n_in,
                              void* d_out, int out_size, void* d_ws, size_t ws_size,
                              hipStream_t stream) {
  const float* in_ftrs  = (const float*)d_in[0];
  const float* out_ftrs = (const float*)d_in[1];
  const float* eWih  = (const float*)d_in[2];
  const float* eWhh  = (const float*)d_in[3];
  const float* ebih  = (const float*)d_in[4];
  const float* ebhh  = (const float*)d_in[5];
  const float* dWih  = (const float*)d_in[6];
  const float* dWhh  = (const float*)d_in[7];
  const float* dbih  = (const float*)d_in[8];
  const float* dbhh  = (const float*)d_in[9];
  const float* attnW = (const float*)d_in[10];
  const float* attnb = (const float*)d_in[11];
  const float* cW    = (const float*)d_in[12];
  const float* cb    = (const float*)d_in[13];
  const float* oW    = (const float*)d_in[14];
  const float* ob    = (const float*)d_in[15];

  float* ws    = (float*)d_ws;
  float* hb0   = ws + OFF_HB0;
  float* hb1   = ws + OFF_HB1;
  float* ctx   = ws + OFF_CTX;
  float* Ep    = ws + OFF_EP;
  float* mlp   = ws + OFF_ML;
  float* cterm = ws + OFF_CTERM;
  float* hgru  = ws + OFF_HGRU;
  float* xte   = ws + OFF_XTE;
  float* xtd   = ws + OFF_XTD;

  hipMemsetAsync(d_ws, 0, WS_FLOATS * sizeof(float), stream);
  transpose_kernel<<<SIN_ * B_ / 256, 256, 0, stream>>>(in_ftrs, xte, SIN_);
  transpose_kernel<<<SOUT_ * B_ / 256, 256, 0, stream>>>(out_ftrs, xtd, SOUT_);

  // ---- encoder: h_p in hb[p&1]; step p writes h_{p+1} (buffer also holds h_{p-1})
  for (int p = 0; p < SIN_; ++p) {
    float* hin  = (p & 1) ? hb1 : hb0;
    float* hout = (p & 1) ? hb0 : hb1;
    stepT_kernel<true><<<256, 256, 0, stream>>>(
        xte, p, eWih, eWhh, ebih, ebhh, attnW, attnb, hin, hout, Ep, mlp, ctx);
  }
  // tail: h_1024 in hb0, h_1023 in hb1
  ctx_tail_kernel<<<256, 256, 0, stream>>>(1023, hb1, Ep, mlp, ctx);
  energy_tail_kernel<<<256, 256, 0, stream>>>(hb0, attnW, attnb, Ep + (size_t)(1024 % 3) * 2048);
  ctx_tail_kernel<<<256, 256, 0, stream>>>(1024, hb0, Ep, mlp, ctx);
  // cterm = cW[:,H:2H]*(ctx/l) + cb   (final l in slot 0 -> mlp+64)
  linT_kernel<<<128, 256, 0, stream>>>(ctx, cW, 2 * H_, H_, nullptr, cb, mlp + 64, cterm, H_, 0);

  // ---- decoder: hgru = GRU(h_state, y_s); h_state = cW[:,0:H]*hgru + cterm
  for (int s = 0; s < SOUT_; ++s) {
    stepT_kernel<false><<<256, 256, 0, stream>>>(
        xtd, s, dWih, dWhh, dbih, dbhh, nullptr, nullptr, hb0, hgru,
        nullptr, nullptr, nullptr);
    if (s + 1 < SOUT_)
      linT_kernel<<<128, 256, 0, stream>>>(hgru, cW, 2 * H_, 0, cterm, nullptr, nullptr, hb0, H_, 0);
  }

  // ---- final projection (row-major output [B][OUT])
  linT_kernel<<<64, 256, 0, stream>>>(hgru, oW, H_, 0, nullptr, ob, nullptr, (float*)d_out, OUT_, 1);

  (void)in_sizes; (void)n_in; (void)out_size; (void)ws_size;
}

// Round 3
// 26905.515 us; speedup vs baseline: 2.4070x; 1.6987x over previous
//
#include <hip/hip_runtime.h>
#include <cstdint>
#include <cstddef>

// ---------------------------------------------------------------------------
// AttentionalSeq2seq on MI355X — round 2: MFMA (bf16-split 3-pass) recurrence.
// Per step: G[4096][64] = A_packed @ packed(h) via mfma_f32_16x16x32_bf16,
// rows permuted j*4+gate so each lane's 4 C-regs = (r,z,n,attn|hstate) for one
// (j,b). Weights pre-packed once into fragment layout; h packed by epilogue.
// Decoder: Whh_eff = dWhh@cW1 precomputed (one-time MFMA GEMM) -> 1 dispatch
// per decode step. Encoder keeps fused online-softmax attention.
// ---------------------------------------------------------------------------

typedef short bshort8 __attribute__((ext_vector_type(8)));
typedef float floatx4 __attribute__((ext_vector_type(4)));

namespace {
constexpr int H_ = 1024, SIN_ = 1024, SOUT_ = 256, OUT_ = 512;
constexpr int KCF = 128;          // fp32 linT staging chunk
// workspace byte offsets
constexpr size_t B_HT0 = 0;                         // h fp32 ping [1024][64]
constexpr size_t B_HT1 = B_HT0 + 262144;            // h fp32 pong
constexpr size_t B_CTX = B_HT1 + 262144;            // ctx accum [1024][64]
constexpr size_t B_EP  = B_CTX + 262144;            // energy partials [3][64][64]
constexpr size_t B_ML  = B_EP + 49152;              // (m,l) [2][2][64]
constexpr size_t B_PKE = B_ML + 1024;               // packed enc h: 2 buf x (hi+lo 131072 shorts)
constexpr size_t ZERO_BYTES = B_PKE + 524288;
constexpr size_t B_PKD = ZERO_BYTES;                // packed dec hgru: 2 buf
constexpr size_t B_CTERM = B_PKD + 524288;          // cW2@context+cb [1024][64]
constexpr size_t B_HGRU  = B_CTERM + 262144;        // decoder hgru fp32
constexpr size_t B_BIAS  = B_HGRU + 262144;         // dWhh@cterm [3072][64]
constexpr size_t B_XTE   = B_BIAS + 786432;         // enc x transposed
constexpr size_t B_XTD   = B_XTE + 262144;          // dec x transposed
constexpr size_t B_AENC  = B_XTD + 65536;           // A_enc packed hi|lo (16MB)
constexpr size_t B_ADEC0 = B_AENC + 16777216;       // A_dec0 packed (16MB)
constexpr size_t B_AEFF  = B_ADEC0 + 16777216;      // A_eff packed (16MB)
constexpr size_t B_BCW   = B_AEFF + 16777216;       // cW1 packed B [1024][1024] (4MB)
constexpr size_t A_LO = 4194304;   // shorts: lo half offset inside A buffers
constexpr size_t BP_LO = 65536;    // shorts: lo half offset inside packed-h
constexpr size_t BC_LO = 1048576;  // shorts: lo half offset inside packed cW1
}  // namespace

__device__ __forceinline__ short f2bf(float f) {
  unsigned int u = __builtin_bit_cast(unsigned int, f);
  u += 0x7FFFu + ((u >> 16) & 1u);
  return (short)(u >> 16);
}
__device__ __forceinline__ float bf2f(short s) {
  unsigned int u = ((unsigned int)(unsigned short)s) << 16;
  return __builtin_bit_cast(float, u);
}
__device__ __forceinline__ float sigm(float x) { return 1.f / (1.f + expf(-x)); }

#define MFMA16(a, b, c) __builtin_amdgcn_mfma_f32_16x16x32_bf16(a, b, c, 0, 0, 0)

// ---------------- one-time pack kernels ----------------
// A pack: perm row = j*4+g. g<3: W3 row (g*1024+j); g==3: R3 row j (stride r3s).
// Frag layout: hi[((mt*32+kb)*64+lane)*8+e], lo at +A_LO. Optional dup of g==3
// rows into dst2 (for A_eff's cW1 gate).
__global__ __launch_bounds__(256) void pack_A(
    const float* __restrict__ W3, const float* __restrict__ R3, int r3s,
    short* __restrict__ dst, short* __restrict__ dst2) {
  int idx = blockIdx.x * 256 + threadIdx.x;   // (mt,kb,lane)
  int lane = idx & 63, kb = (idx >> 6) & 31, mt = idx >> 11;
  int row = mt * 16 + (lane & 15);
  int g = row & 3, j = row >> 2;
  int k0 = kb * 32 + (lane >> 4) * 8;
  const float* src = (g < 3) ? W3 + (size_t)(g * 1024 + j) * 1024 + k0
                             : R3 + (size_t)j * r3s + k0;
  bshort8 hi, lo;
#pragma unroll
  for (int e = 0; e < 8; ++e) {
    float f = src[e];
    short h = f2bf(f);
    hi[e] = h; lo[e] = f2bf(f - bf2f(h));
  }
  size_t o = (size_t)idx * 8;
  *reinterpret_cast<bshort8*>(dst + o) = hi;
  *reinterpret_cast<bshort8*>(dst + A_LO + o) = lo;
  if (dst2 != nullptr && g == 3) {
    *reinterpret_cast<bshort8*>(dst2 + o) = hi;
    *reinterpret_cast<bshort8*>(dst2 + A_LO + o) = lo;
  }
}

// B pack of cW1: B[k][n] = cW[k*2048 + n]; hi[((kb*64+nb)*64+lane)*8+e], lo +BC_LO.
__global__ __launch_bounds__(256) void pack_Bcw(const float* __restrict__ cW,
                                                short* __restrict__ dst) {
  int idx = blockIdx.x * 256 + threadIdx.x;   // (kb, nb, lane)
  int lane = idx & 63, nb = (idx >> 6) & 63, kb = idx >> 12;
  int n = nb * 16 + (lane & 15);
  int k0 = kb * 32 + (lane >> 4) * 8;
  bshort8 hi, lo;
#pragma unroll
  for (int e = 0; e < 8; ++e) {
    float f = cW[(size_t)(k0 + e) * 2048 + n];
    short h = f2bf(f);
    hi[e] = h; lo[e] = f2bf(f - bf2f(h));
  }
  size_t o = (size_t)idx * 8;
  *reinterpret_cast<bshort8*>(dst + o) = hi;
  *reinterpret_cast<bshort8*>(dst + BC_LO + o) = lo;
}

// One-time GEMM: Whh_eff = dWhh_perm @ cW1 -> write A_eff frags (gates 0..2).
// wave = (mt, nb): mt = wid>>6 (256), nb = wid&63 (64). Direct global frags.
__global__ __launch_bounds__(256) void gemm_eff(
    const short* __restrict__ Adec, const short* __restrict__ Bcw,
    short* __restrict__ Aeff) {
  const int t = threadIdx.x, l = t & 63;
  const int w = __builtin_amdgcn_readfirstlane(t >> 6);
  const int wid = blockIdx.x * 4 + w;
  const int mt = wid >> 6, nb = wid & 63;
  floatx4 aHH = (floatx4)0.f, aLH = (floatx4)0.f, aHL = (floatx4)0.f;
  for (int kb = 0; kb < 32; ++kb) {
    size_t ao = (((size_t)mt * 32 + kb) * 64 + l) * 8;
    size_t bo = (((size_t)kb * 64 + nb) * 64 + l) * 8;
    bshort8 ah = *reinterpret_cast<const bshort8*>(Adec + ao);
    bshort8 al = *reinterpret_cast<const bshort8*>(Adec + A_LO + ao);
    bshort8 bh = *reinterpret_cast<const bshort8*>(Bcw + bo);
    bshort8 bl = *reinterpret_cast<const bshort8*>(Bcw + BC_LO + bo);
    aHH = MFMA16(ah, bh, aHH);
    aLH = MFMA16(al, bh, aLH);
    aHL = MFMA16(ah, bl, aHL);
  }
  floatx4 s = aHH + aLH + aHL;
#pragma unroll
  for (int reg = 0; reg < 3; ++reg) {   // skip gate 3 (cW1 rows, packed by P2)
    float v = s[reg];
    int row = mt * 16 + (l >> 4) * 4 + reg;
    int kA = nb * 16 + (l & 15);
    short hi = f2bf(v), lo = f2bf(v - bf2f(hi));
    size_t off = (((size_t)mt * 32 + (kA >> 5)) * 64 +
                  ((row & 15) + 16 * ((kA >> 3) & 3))) * 8 + (kA & 7);
    Aeff[off] = hi;
    Aeff[A_LO + off] = lo;
  }
}

// ---------------- the per-step MFMA kernel ----------------
// MODE 0=ENC (gate3=attn, energy+ctx fused), 1=DEC0 (hcur from hT_in),
// 2=DECN (gates += biasEff, hcur = acc3 + cterm).
template <int MODE>
__global__ __launch_bounds__(256) void gemm_step(
    const short* __restrict__ Afrag, const short* __restrict__ Bpk,
    short* __restrict__ BpkOut,
    const float* __restrict__ xT, int p,
    const float* __restrict__ Wih, const float* __restrict__ bih,
    const float* __restrict__ bhh, const float* __restrict__ attnb,
    const float* __restrict__ hT_in, float* __restrict__ hT_out,
    const float* __restrict__ biasEff, const float* __restrict__ cterm,
    float* __restrict__ Epart, float* __restrict__ ml, float* __restrict__ ctxT) {
  __shared__ __align__(16) short ldsB[16384];  // 2 dbuf x (hi 4096 + lo 4096)
  const int t = threadIdx.x, l = t & 63;
  const int w = __builtin_amdgcn_readfirstlane(t >> 6);
  const int mt = blockIdx.x * 4 + w;           // 0..255

  if (MODE == 0) {
    if (blockIdx.x == 0) {  // rotate-zero slot used at step p+1
      float* z = Epart + (size_t)((p + 1) % 3) * 4096;
#pragma unroll
      for (int i = 0; i < 16; ++i) z[t + i * 256] = 0.f;
    }
    if (p >= 2) {  // online-softmax ctx update for u = p-1 (h_{p-1} in hT_out)
      const float* Eb = Epart + (size_t)((p - 1) % 3) * 4096;
      float e = 0.f;
      for (int g = 0; g < 64; ++g) e += Eb[g * 64 + l];
      const float* mlr = ml + (size_t)(p & 1) * 128;          // slot (u-1)&1
      float m_old = mlr[l], l_old = mlr[64 + l];
      float m_new, sc, wgt, l_new;
      if (l_old == 0.f) { m_new = e; sc = 0.f; wgt = 1.f; l_new = 1.f; }
      else {
        m_new = fmaxf(m_old, e);
        sc = expf(m_old - m_new);
        wgt = expf(e - m_new);
        l_new = fmaf(l_old, sc, wgt);
      }
      if (blockIdx.x == 0 && w == 0) {
        float* mlw = ml + (size_t)((p - 1) & 1) * 128;
        mlw[l] = m_new; mlw[64 + l] = l_new;
      }
      int j = mt * 4 + (l >> 4);
#pragma unroll
      for (int nb = 0; nb < 4; ++nb) {
        int b = nb * 16 + (l & 15);
        float scb = __shfl(sc, b);
        float wgb = __shfl(wgt, b);
        size_t idx = (size_t)j * 64 + b;
        ctxT[idx] = fmaf(ctxT[idx], scb, wgb * hT_out[idx]);
      }
    }
  }

  floatx4 aHH[4], aLH[4], aHL[4];
#pragma unroll
  for (int i = 0; i < 4; ++i) { aHH[i] = (floatx4)0.f; aLH[i] = (floatx4)0.f; aHL[i] = (floatx4)0.f; }

  // stage chunk c (64 k) of packed B into ldsB[dbuf]: linear copy, 4 instr/wave
  auto stage = [&](int c, int dbuf) {
#pragma unroll
    for (int half = 0; half < 2; ++half)
#pragma unroll
      for (int i = 0; i < 2; ++i) {
        const short* g = Bpk + half * BP_LO + (size_t)c * 4096 + (w * 2 + i) * 512 + l * 8;
        short* lp = ldsB + dbuf * 8192 + half * 4096 + (w * 2 + i) * 512 + l * 8;
        __builtin_amdgcn_global_load_lds(
            (const __attribute__((address_space(1))) void*)g,
            (__attribute__((address_space(3))) void*)lp, 16, 0, 0);
      }
  };

  stage(0, 0);
  asm volatile("s_waitcnt vmcnt(0)" ::: "memory");
  __syncthreads();
  for (int c = 0; c < 16; ++c) {
    if (c + 1 < 16) stage(c + 1, (c + 1) & 1);
    const short* lb = ldsB + (c & 1) * 8192;
#pragma unroll
    for (int kb = 0; kb < 2; ++kb) {
      size_t ao = (((size_t)mt * 32 + (c * 2 + kb)) * 64 + l) * 8;
      bshort8 ah = *reinterpret_cast<const bshort8*>(Afrag + ao);
      bshort8 al = *reinterpret_cast<const bshort8*>(Afrag + A_LO + ao);
#pragma unroll
      for (int nb = 0; nb < 4; ++nb) {
        bshort8 bh = *reinterpret_cast<const bshort8*>(lb + (kb * 4 + nb) * 512 + l * 8);
        bshort8 bl = *reinterpret_cast<const bshort8*>(lb + 4096 + (kb * 4 + nb) * 512 + l * 8);
        aHH[nb] = MFMA16(ah, bh, aHH[nb]);
        aLH[nb] = MFMA16(al, bh, aLH[nb]);
        aHL[nb] = MFMA16(ah, bl, aHL[nb]);
      }
    }
    asm volatile("s_waitcnt vmcnt(0)" ::: "memory");
    __syncthreads();
  }

  // ---- epilogue: lane-local gate math for j = mt*4 + (l>>4), b = nb*16+(l&15)
  const int j = mt * 4 + (l >> 4);
  const float wih0 = Wih[j], wih1 = Wih[1024 + j], wih2 = Wih[2048 + j];
  const float bi0 = bih[j], bi1 = bih[1024 + j], bi2 = bih[2048 + j];
  const float bh0 = bhh[j], bh1 = bhh[1024 + j], bh2 = bhh[2048 + j];
  const float anb = (MODE == 0) ? attnb[j] : 0.f;
  float eacc[4];
#pragma unroll
  for (int nb = 0; nb < 4; ++nb) {
    const int b = nb * 16 + (l & 15);
    floatx4 s = aHH[nb] + aLH[nb] + aHL[nb];
    float gr = s[0] + bh0, gz = s[1] + bh1, gn = s[2] + bh2;
    if (MODE == 2) {
      gr += biasEff[(size_t)(0 * 1024 + j) * 64 + b];
      gz += biasEff[(size_t)(1 * 1024 + j) * 64 + b];
      gn += biasEff[(size_t)(2 * 1024 + j) * 64 + b];
    }
    const float xv = xT[(size_t)p * 64 + b];
    const float r = sigm(fmaf(xv, wih0, bi0) + gr);
    const float z = sigm(fmaf(xv, wih1, bi1) + gz);
    const float n = tanhf(fmaf(xv, wih2, bi2) + fmaf(r, gn, 0.f));
    float hcur;
    if (MODE == 2) hcur = s[3] + cterm[(size_t)j * 64 + b];
    else           hcur = hT_in[(size_t)j * 64 + b];
    const float hnew = fmaf(z, hcur - n, n);
    hT_out[(size_t)j * 64 + b] = hnew;
    // pack hnew (bf16 hi/lo) into B-frag layout for the next step
    short hi = f2bf(hnew), lo = f2bf(hnew - bf2f(hi));
    size_t pk = (((size_t)(j >> 5) * 4 + nb) * 64 + (b & 15) + 16 * ((j >> 3) & 3)) * 8 + (j & 7);
    BpkOut[pk] = hi;
    BpkOut[BP_LO + pk] = lo;
    if (MODE == 0) eacc[nb] = hcur * (s[3] + anb);
  }
  if (MODE == 0) {  // energy partials: reduce over the wave's 4 js, b = lane
#pragma unroll
    for (int nb = 0; nb < 4; ++nb) {
      float e = eacc[nb];
      e += __shfl_xor(e, 16);
      e += __shfl_xor(e, 32);
      eacc[nb] = e;
    }
    int g = l >> 4;
    float ev = (g == 0) ? eacc[0] : (g == 1) ? eacc[1] : (g == 2) ? eacc[2] : eacc[3];
    atomicAdd(&Epart[(size_t)(p % 3) * 4096 + (size_t)blockIdx.x * 64 + l], ev);
  }
}

// ---------------- fp32 helper kernels (tails / linears) ----------------
__device__ __forceinline__ void stage_chunk_f32(const float* __restrict__ srcT,
                                                float* lbuf, int c, int w, int l) {
#pragma unroll
  for (int i = 0; i < 8; ++i) {
    const int krow = c * KCF + w * 32 + i * 4 + (l >> 4);
    const float* g = srcT + (size_t)krow * 64 + (l & 15) * 4;
    float* lp = lbuf + (w * 2048 + i * 256 + l * 4);
    __builtin_amdgcn_global_load_lds(
        (const __attribute__((address_space(1))) void*)g,
        (__attribute__((address_space(3))) void*)lp, 16, 0, 0);
  }
}

// dstT[j][b] = sum_k W[j*ws+woff+k]*srcT[k][b] (*1/linv[b]) (+bias[j]) (+addT[j][b])
__global__ __launch_bounds__(256) void linT_kernel(
    const float* __restrict__ srcT, const float* __restrict__ W, int wstride, int woff,
    const float* __restrict__ addT, const float* __restrict__ bias,
    const float* __restrict__ linv, float* __restrict__ dst, int NJ, int rowmajor_out) {
  __shared__ __attribute__((aligned(16))) float hs[2][KCF * 64];
  const int t = threadIdx.x, l = t & 63;
  const int w = __builtin_amdgcn_readfirstlane(t >> 6);
  const int j0 = (blockIdx.x * 4 + w) * 2;
  const float* W0 = W + (size_t)j0 * wstride + woff;
  const float* W1 = W + (size_t)(j0 + 1) * wstride + woff;
  float a0 = 0.f, a1 = 0.f;
  stage_chunk_f32(srcT, &hs[0][0], 0, w, l);
  asm volatile("s_waitcnt vmcnt(0)" ::: "memory");
  __syncthreads();
  for (int c = 0; c < H_ / KCF; ++c) {
    if (c + 1 < H_ / KCF) stage_chunk_f32(srcT, &hs[(c + 1) & 1][0], c + 1, w, l);
    const float* hp = &hs[c & 1][0];
    const int kb = c * KCF;
#pragma unroll 32
    for (int kk = 0; kk < KCF; ++kk) {
      float h = hp[kk * 64 + l];
      a0 = fmaf(h, W0[kb + kk], a0);
      a1 = fmaf(h, W1[kb + kk], a1);
    }
    asm volatile("s_waitcnt vmcnt(0)" ::: "memory");
    __syncthreads();
  }
  const float inv = linv ? 1.f / linv[l] : 1.f;
#pragma unroll
  for (int ci = 0; ci < 2; ++ci) {
    const int j = j0 + ci;
    float val = (ci ? a1 : a0) * inv;
    if (bias) val += bias[j];
    if (addT) val += addT[(size_t)j * 64 + l];
    if (rowmajor_out) dst[(size_t)l * NJ + j] = val;
    else              dst[(size_t)j * 64 + l] = val;
  }
}

// energy of h_1024 into Ebuf slots (j&31)
__global__ __launch_bounds__(256) void energy_tail_kernel(
    const float* __restrict__ hT, const float* __restrict__ attnW,
    const float* __restrict__ attnb, float* __restrict__ Ebuf) {
  __shared__ __attribute__((aligned(16))) float hs[2][KCF * 64];
  const int t = threadIdx.x, l = t & 63;
  const int w = __builtin_amdgcn_readfirstlane(t >> 6);
  const int j = blockIdx.x * 4 + w;
  const float* Wa = attnW + (size_t)j * H_;
  float aA = 0.f;
  stage_chunk_f32(hT, &hs[0][0], 0, w, l);
  asm volatile("s_waitcnt vmcnt(0)" ::: "memory");
  __syncthreads();
  for (int c = 0; c < H_ / KCF; ++c) {
    if (c + 1 < H_ / KCF) stage_chunk_f32(hT, &hs[(c + 1) & 1][0], c + 1, w, l);
    const float* hp = &hs[c & 1][0];
    const int kb = c * KCF;
#pragma unroll 32
    for (int kk = 0; kk < KCF; ++kk) aA = fmaf(hp[kk * 64 + l], Wa[kb + kk], aA);
    asm volatile("s_waitcnt vmcnt(0)" ::: "memory");
    __syncthreads();
  }
  atomicAdd(&Ebuf[(size_t)(j & 31) * 64 + l], hT[(size_t)j * 64 + l] * (aA + attnb[j]));
}

// ctx update tail (64 partial slots)
__global__ __launch_bounds__(256) void ctx_tail64(
    int u, const float* __restrict__ hTu, const float* __restrict__ Ep,
    float* __restrict__ ml, float* __restrict__ ctxT) {
  const int t = threadIdx.x, l = t & 63;
  const int w = __builtin_amdgcn_readfirstlane(t >> 6);
  const int j = blockIdx.x * 4 + w;
  const float* Eb = Ep + (size_t)(u % 3) * 4096;
  float e = 0.f;
  for (int g = 0; g < 64; ++g) e += Eb[g * 64 + l];
  const float* mlr = ml + (size_t)((u - 1) & 1) * 128;
  float m_old = mlr[l], l_old = mlr[64 + l];
  float m_new, sc, wgt, l_new;
  if (l_old == 0.f) { m_new = e; sc = 0.f; wgt = 1.f; l_new = 1.f; }
  else {
    m_new = fmaxf(m_old, e);
    sc = expf(m_old - m_new);
    wgt = expf(e - m_new);
    l_new = fmaf(l_old, sc, wgt);
  }
  if (j == 0) {
    float* mlw = ml + (size_t)(u & 1) * 128;
    mlw[l] = m_new; mlw[64 + l] = l_new;
  }
  size_t idx = (size_t)j * 64 + l;
  ctxT[idx] = fmaf(ctxT[idx], sc, wgt * hTu[idx]);
}

// x[b][s] -> xT[s][b]
__global__ __launch_bounds__(256) void transpose_kernel(
    const float* __restrict__ x, float* __restrict__ xT, int S) {
  int idx = blockIdx.x * 256 + threadIdx.x;
  int s = idx >> 6, b = idx & 63;
  xT[idx] = x[(size_t)b * S + s];
}

extern "C" void kernel_launch(void* const* d_in, const int* in_sizes, int n_in,
                              void* d_out, int out_size, void* d_ws, size_t ws_size,
                              hipStream_t stream) {
  const float* in_ftrs  = (const float*)d_in[0];
  const float* out_ftrs = (const float*)d_in[1];
  const float* eWih  = (const float*)d_in[2];
  const float* eWhh  = (const float*)d_in[3];
  const float* ebih  = (const float*)d_in[4];
  const float* ebhh  = (const float*)d_in[5];
  const float* dWih  = (const float*)d_in[6];
  const float* dWhh  = (const float*)d_in[7];
  const float* dbih  = (const float*)d_in[8];
  const float* dbhh  = (const float*)d_in[9];
  const float* attnW = (const float*)d_in[10];
  const float* attnb = (const float*)d_in[11];
  const float* cW    = (const float*)d_in[12];
  const float* cb    = (const float*)d_in[13];
  const float* oW    = (const float*)d_in[14];
  const float* ob    = (const float*)d_in[15];

  char* wsb = (char*)d_ws;
  float* ht0   = (float*)(wsb + B_HT0);
  float* ht1   = (float*)(wsb + B_HT1);
  float* ctx   = (float*)(wsb + B_CTX);
  float* Ep    = (float*)(wsb + B_EP);
  float* mlp   = (float*)(wsb + B_ML);
  short* pke   = (short*)(wsb + B_PKE);   // 2 x 131072 shorts
  short* pkd   = (short*)(wsb + B_PKD);
  float* cterm = (float*)(wsb + B_CTERM);
  float* hgru  = (float*)(wsb + B_HGRU);
  float* bEff  = (float*)(wsb + B_BIAS);
  float* xte   = (float*)(wsb + B_XTE);
  float* xtd   = (float*)(wsb + B_XTD);
  short* Aenc  = (short*)(wsb + B_AENC);
  short* Adec0 = (short*)(wsb + B_ADEC0);
  short* Aeff  = (short*)(wsb + B_AEFF);
  short* Bcw   = (short*)(wsb + B_BCW);

  hipMemsetAsync(d_ws, 0, ZERO_BYTES, stream);
  transpose_kernel<<<SIN_ * 64 / 256, 256, 0, stream>>>(in_ftrs, xte, SIN_);
  transpose_kernel<<<SOUT_ * 64 / 256, 256, 0, stream>>>(out_ftrs, xtd, SOUT_);

  // one-time packs + Whh_eff GEMM
  pack_A<<<2048, 256, 0, stream>>>(eWhh, attnW, 1024, Aenc, nullptr);
  pack_A<<<2048, 256, 0, stream>>>(dWhh, cW, 2048, Adec0, Aeff);  // g3 = cW1 rows
  pack_Bcw<<<512, 256, 0, stream>>>(cW, Bcw);
  gemm_eff<<<4096, 256, 0, stream>>>(Adec0, Bcw, Aeff);

  // ---- encoder: step p computes h_{p+1}; B = packed(h_p) in pke[p&1]
  for (int p = 0; p < SIN_; ++p) {
    float* hin  = (p & 1) ? ht1 : ht0;
    float* hout = (p & 1) ? ht0 : ht1;
    gemm_step<0><<<64, 256, 0, stream>>>(
        Aenc, pke + (size_t)(p & 1) * 131072, pke + (size_t)((p + 1) & 1) * 131072,
        xte, p, eWih, ebih, ebhh, attnb, hin, hout, nullptr, nullptr, Ep, mlp, ctx);
  }
  // tails: h_1024 in ht0, h_1023 in ht1
  ctx_tail64<<<256, 256, 0, stream>>>(1023, ht1, Ep, mlp, ctx);
  energy_tail_kernel<<<256, 256, 0, stream>>>(ht0, attnW, attnb, Ep + (size_t)(1024 % 3) * 4096);
  ctx_tail64<<<256, 256, 0, stream>>>(1024, ht0, Ep, mlp, ctx);
  // cterm = cW2 * (ctx / l) + cb ; final l in slot 0 -> mlp+64
  linT_kernel<<<128, 256, 0, stream>>>(ctx, cW, 2 * H_, H_, nullptr, cb, mlp + 64, cterm, H_, 0);
  // bias_eff = dWhh @ cterm  [3072][64]
  linT_kernel<<<384, 256, 0, stream>>>(cterm, dWhh, H_, 0, nullptr, nullptr, nullptr, bEff, 3072, 0);

  // ---- decoder: 1 GEMM dispatch per step
  gemm_step<1><<<64, 256, 0, stream>>>(
      Adec0, pke + 0, pkd + 0, xtd, 0, dWih, dbih, dbhh, nullptr,
      ht0, hgru, nullptr, nullptr, nullptr, nullptr, nullptr);
  for (int s = 1; s < SOUT_; ++s) {
    gemm_step<2><<<64, 256, 0, stream>>>(
        Aeff, pkd + (size_t)((s + 1) & 1) * 131072, pkd + (size_t)(s & 1) * 131072,
        xtd, s, dWih, dbih, dbhh, nullptr, nullptr, hgru, bEff, cterm,
        nullptr, nullptr, nullptr);
  }

  // ---- final projection: out = oW @ hgru_255 + ob  (row-major [64][512])
  linT_kernel<<<64, 256, 0, stream>>>(hgru, oW, H_, 0, nullptr, ob, nullptr, (float*)d_out, OUT_, 1);

  (void)in_sizes; (void)n_in; (void)out_size; (void)ws_size;
}